// Round 10
// baseline (261.413 us; speedup 1.0000x reference)
//
#include <hip/hip_runtime.h>

typedef _Float16 f16;
typedef __attribute__((ext_vector_type(4))) _Float16 f16x4;
typedef __attribute__((ext_vector_type(8))) _Float16 f16x8;
typedef __attribute__((ext_vector_type(4))) float f32x4;

#define MFMA16(a, b, c) __builtin_amdgcn_mfma_f32_16x16x32_f16((a), (b), (c), 0, 0, 0)

__device__ __forceinline__ f16x8 cvt8(float4 a, float4 b) {
    f16x8 r;
    r[0] = (f16)a.x; r[1] = (f16)a.y; r[2] = (f16)a.z; r[3] = (f16)a.w;
    r[4] = (f16)b.x; r[5] = (f16)b.y; r[6] = (f16)b.z; r[7] = (f16)b.w;
    return r;
}

__device__ __forceinline__ f16x8 zero8() {
    f16x8 z;
#pragma unroll
    for (int q = 0; q < 8; ++q) z[q] = (f16)0.0f;
    return z;
}

// ---------------- pre-kernel: fp16 weights + fused bias constants into ws ----
__global__ void prep_kernel(const float* __restrict__ w_ih, const float* __restrict__ w_hh,
                            const float* __restrict__ b_ih, const float* __restrict__ b_hh,
                            const float* __restrict__ b_iah, const float* __restrict__ b_oah,
                            const float* __restrict__ W_in, const float* __restrict__ bias_in,
                            const float* __restrict__ W_out, const float* __restrict__ bias_out,
                            f16* __restrict__ Wc, f16* __restrict__ Whh, f16* __restrict__ Wih,
                            float* __restrict__ cstA, float* __restrict__ cstB,
                            float* __restrict__ biasc) {
    const int gid = blockIdx.x * 256 + threadIdx.x;
    const int gstride = gridDim.x * 256;
    for (int i = gid; i < 8192; i += gstride)
        Wc[i] = (f16)(i < 4096 ? W_in[i] : W_out[i - 4096]);
    for (int i = gid; i < 12288; i += gstride) Whh[i] = (f16)w_hh[i];   // [192][64]
    for (int i = gid; i < 24576; i += gstride) Wih[i] = (f16)w_ih[i];   // [192][128]
    for (int job = gid; job < 768; job += gstride) {
        const int g = job >> 2, q = job & 3;
        float s = (q == 0) ? b_ih[g] : 0.0f;
        const float* wr = w_ih + g * 128 + q * 32;
        for (int i = 0; i < 32; ++i)
            s += wr[i] * ((q * 32 + i < 64) ? b_iah[q * 32 + i] : b_oah[q * 32 + i - 64]);
        atomicAdd(&cstA[g], s);
    }
    for (int g = gid; g < 192; g += gstride) cstB[g] = b_hh[g];
    for (int j = gid; j < 128; j += gstride) biasc[j] = (j < 64) ? bias_in[j] : bias_out[j - 64];
}

__global__ void zero_kernel(float* __restrict__ cstA) {
    if (threadIdx.x < 192) cstA[threadIdx.x] = 0.0f;
}

// ---------------- fused main kernel (R3 structure + odd-stride pads) ---------
// LDS 64640 B:
//   hT  [128][202] f16 @0       (51712)  h_cat^T   (odd dword stride: no conflicts)
//   hA  [2][16][202] f16 @51712 (12928)  staged A tile (half-major)
//   inp [200][138] f16 @0       (55200)  aliases hT/hA after phase 2
__global__ __launch_bounds__(512, 2) void gru_fused(
    const float* __restrict__ A, const float* __restrict__ hidden,
    const f16* __restrict__ Wc, const f16* __restrict__ Whh, const f16* __restrict__ Wih,
    const float* __restrict__ cstA, const float* __restrict__ cstB,
    const float* __restrict__ biasc, float* __restrict__ out) {
    __shared__ __align__(16) char lds_raw[64640];
    f16* hT  = (f16*)lds_raw;             // [128][202]
    f16* hA  = (f16*)(lds_raw + 51712);   // [2][16][202]
    f16* inp = (f16*)lds_raw;             // [200][138] alias

    const int b = blockIdx.x;
    const float* Ab = A + (size_t)b * 80000;      // [400][200]
    const float* hb = hidden + (size_t)b * 12800; // [200][64]
    float* ob = out + (size_t)b * 12800;

    const int tid = threadIdx.x;
    const int w   = tid >> 6;
    const int l   = tid & 63;
    const int l15 = l & 15;
    const int lg  = l >> 4;

    // ---- Phase 1: hT[j][m] = f16(hidden[m,:]@Wc[j,:] + biasc[j]) ----
    for (int mt = w; mt < 13; mt += 8) {
        const int m  = mt * 16 + l15;
        const int mc = m < 200 ? m : 199;
        const float* hrow = hb + mc * 64;
        float4 r0 = *(const float4*)(hrow + lg * 8);
        float4 r1 = *(const float4*)(hrow + lg * 8 + 4);
        float4 r2 = *(const float4*)(hrow + 32 + lg * 8);
        float4 r3 = *(const float4*)(hrow + 32 + lg * 8 + 4);
        f16x8 a0 = cvt8(r0, r1), a1 = cvt8(r2, r3);
        const int m0 = mt * 16 + lg * 4;
#pragma unroll
        for (int jt = 0; jt < 8; ++jt) {
            const int j = jt * 16 + l15;
            f32x4 acc = {0.f, 0.f, 0.f, 0.f};
            acc = MFMA16(a0, *(const f16x8*)(Wc + j * 64 + lg * 8), acc);
            acc = MFMA16(a1, *(const f16x8*)(Wc + j * 64 + 32 + lg * 8), acc);
            const float bc = biasc[j];
            if (m0 < 200) {
                f16x4 pk;
                pk[0] = (f16)(acc[0] + bc); pk[1] = (f16)(acc[1] + bc);
                pk[2] = (f16)(acc[2] + bc); pk[3] = (f16)(acc[3] + bc);
                *(f16x4*)(hT + j * 202 + m0) = pk;
            }
        }
    }
    __syncthreads();

    // ---- Phase 2: inputs = A_cat @ h_cat, A staged coalesced via LDS ----
    // wave w -> output col-tile [w*16, w*16+16), A-half = w>>2.
    const int hf = w >> 2;
    const f16* hAp = hA + hf * 3232 + l15 * 202;         // 3232 = 16*202
    const f16* hTp = hT + (w * 16 + l15) * 202;

    // staging map: 1600 float4-units (2 halves x 16 rows x 50 units)
    int s_h[4], s_row[4], s_unit[4]; bool s_act[4];
#pragma unroll
    for (int r = 0; r < 4; ++r) {
        const int idx = tid + r * 512;
        s_act[r] = idx < 1600;
        const int ic = s_act[r] ? idx : 0;
        s_h[r] = ic / 800;
        const int rem = ic % 800;
        s_row[r] = rem / 50; s_unit[r] = rem % 50;
    }

    f32x4 accC[13];
#pragma unroll
    for (int t = 0; t < 13; ++t) accC[t] = (f32x4){0.f, 0.f, 0.f, 0.f};

    // stage tile 0
    {
        float4 v[4];
#pragma unroll
        for (int r = 0; r < 4; ++r) if (s_act[r]) {
            const int n = s_row[r];           // tile 0
            const int nc = n < 200 ? n : 199;
            v[r] = *(const float4*)(Ab + (size_t)(s_h[r] * 200 + nc) * 200 + s_unit[r] * 4);
        }
#pragma unroll
        for (int r = 0; r < 4; ++r) if (s_act[r]) {
            f16x4 pk;
            pk[0] = (f16)v[r].x; pk[1] = (f16)v[r].y;
            pk[2] = (f16)v[r].z; pk[3] = (f16)v[r].w;
            *(f16x4*)(hA + s_h[r] * 3232 + s_row[r] * 202 + s_unit[r] * 4) = pk;
        }
    }
    __syncthreads();

#pragma unroll
    for (int t = 0; t < 13; ++t) {
        float4 v[4];
        if (t < 12) {                          // issue next tile's loads early
#pragma unroll
            for (int r = 0; r < 4; ++r) if (s_act[r]) {
                const int n = (t + 1) * 16 + s_row[r];
                const int nc = n < 200 ? n : 199;
                v[r] = *(const float4*)(Ab + (size_t)(s_h[r] * 200 + nc) * 200 + s_unit[r] * 4);
            }
        }
#pragma unroll
        for (int k0 = 0; k0 < 224; k0 += 32) {
            const int koff = (k0 == 192) ? 192 : k0 + lg * 8;  // tail: all lanes at 192
            f16x8 a;
            if (k0 == 192 && lg != 0) a = zero8();
            else                      a = *(const f16x8*)(hAp + koff);
            f16x8 bf = *(const f16x8*)(hTp + koff);
            accC[t] = MFMA16(a, bf, accC[t]);
        }
        __syncthreads();                       // all reads of hA done
        if (t < 12) {
#pragma unroll
            for (int r = 0; r < 4; ++r) if (s_act[r]) {
                f16x4 pk;
                pk[0] = (f16)v[r].x; pk[1] = (f16)v[r].y;
                pk[2] = (f16)v[r].z; pk[3] = (f16)v[r].w;
                *(f16x4*)(hA + s_h[r] * 3232 + s_row[r] * 202 + s_unit[r] * 4) = pk;
            }
        }
        __syncthreads();                       // writes visible
    }

    // spill accC -> inp (hT/hA dead now)
#pragma unroll
    for (int t = 0; t < 13; ++t) {
#pragma unroll
        for (int r = 0; r < 4; ++r) {
            const int n = t * 16 + lg * 4 + r;
            if (n < 200) inp[n * 138 + w * 16 + l15] = (f16)accC[t][r];
        }
    }
    __syncthreads();

    // ---- Phase 3: gi = inputs@w_ih^T, gh = hidden@w_hh^T, gates, store ----
    const int c   = w & 3;    // h-column tile (16 cols)
    const int wm2 = w >> 2;   // 0..1 -> M-tile parity
    const int hcol = c * 16 + l15;
    f16x8 Wf0[4], Wf1[4], Wf2[4];
#pragma unroll
    for (int k = 0; k < 4; ++k) {
        Wf0[k] = *(const f16x8*)(Wih + (hcol      ) * 128 + k * 32 + lg * 8);
        Wf1[k] = *(const f16x8*)(Wih + (64  + hcol) * 128 + k * 32 + lg * 8);
        Wf2[k] = *(const f16x8*)(Wih + (128 + hcol) * 128 + k * 32 + lg * 8);
    }
    f16x8 Hf0[2], Hf1[2], Hf2[2];
#pragma unroll
    for (int k = 0; k < 2; ++k) {
        Hf0[k] = *(const f16x8*)(Whh + (hcol      ) * 64 + k * 32 + lg * 8);
        Hf1[k] = *(const f16x8*)(Whh + (64  + hcol) * 64 + k * 32 + lg * 8);
        Hf2[k] = *(const f16x8*)(Whh + (128 + hcol) * 64 + k * 32 + lg * 8);
    }
    const float cAr = cstA[hcol], cAi = cstA[64 + hcol], cAn = cstA[128 + hcol];
    const float cBr = cstB[hcol], cBi = cstB[64 + hcol], cBn = cstB[128 + hcol];

    for (int t = wm2; t < 13; t += 2) {
        const int n  = t * 16 + l15;
        const int nc = n < 200 ? n : 199;
        f32x4 gir = {0.f,0.f,0.f,0.f}, gii = {0.f,0.f,0.f,0.f}, gin = {0.f,0.f,0.f,0.f};
        f32x4 ghr = {0.f,0.f,0.f,0.f}, ghi = {0.f,0.f,0.f,0.f}, ghn = {0.f,0.f,0.f,0.f};
#pragma unroll
        for (int k = 0; k < 2; ++k) {          // gh first: global loads issue early
            const int h = k * 32 + lg * 8;
            float4 r0 = *(const float4*)(hb + nc * 64 + h);
            float4 r1 = *(const float4*)(hb + nc * 64 + h + 4);
            f16x8 a = cvt8(r0, r1);
            ghr = MFMA16(a, Hf0[k], ghr);
            ghi = MFMA16(a, Hf1[k], ghi);
            ghn = MFMA16(a, Hf2[k], ghn);
        }
#pragma unroll
        for (int k = 0; k < 4; ++k) {          // gi: K = 128, inp in LDS
            f16x8 a = *(const f16x8*)(inp + nc * 138 + k * 32 + lg * 8);
            gir = MFMA16(a, Wf0[k], gir);
            gii = MFMA16(a, Wf1[k], gii);
            gin = MFMA16(a, Wf2[k], gin);
        }
#pragma unroll
        for (int r = 0; r < 4; ++r) {
            const int row = t * 16 + lg * 4 + r;
            if (row < 200) {
                const float hv = hb[row * 64 + hcol];
                const float xr = gir[r] + ghr[r] + cAr + cBr;
                const float xi = gii[r] + ghi[r] + cAi + cBi;
                const float rg = 1.0f / (1.0f + __expf(-xr));
                const float ig = 1.0f / (1.0f + __expf(-xi));
                const float xn = gin[r] + cAn + rg * (ghn[r] + cBn);
                const float e2 = __expf(2.0f * xn);
                const float ng = 1.0f - 2.0f / (e2 + 1.0f);
                ob[row * 64 + hcol] = hv + ig * (ng - hv);
            }
        }
    }
}

extern "C" void kernel_launch(void* const* d_in, const int* in_sizes, int n_in,
                              void* d_out, int out_size, void* d_ws, size_t ws_size,
                              hipStream_t stream) {
    const float* A        = (const float*)d_in[0];
    const float* hidden   = (const float*)d_in[1];
    const float* w_ih     = (const float*)d_in[2];
    const float* w_hh     = (const float*)d_in[3];
    const float* b_ih     = (const float*)d_in[4];
    const float* b_hh     = (const float*)d_in[5];
    const float* b_iah    = (const float*)d_in[6];
    const float* b_oah    = (const float*)d_in[7];
    const float* W_in     = (const float*)d_in[8];
    const float* bias_in  = (const float*)d_in[9];
    const float* W_out    = (const float*)d_in[10];
    const float* bias_out = (const float*)d_in[11];
    float* out = (float*)d_out;

    char* wsb = (char*)d_ws;
    f16* Wc      = (f16*)wsb;            // 8192 f16
    f16* Whh     = Wc + 8192;            // 12288 f16
    f16* Wih     = Whh + 12288;          // 24576 f16
    float* cstA  = (float*)(wsb + 90112);
    float* cstB  = cstA + 192;
    float* biasc = cstB + 192;

    zero_kernel<<<dim3(1), dim3(256), 0, stream>>>(cstA);
    prep_kernel<<<dim3(64), dim3(256), 0, stream>>>(
        w_ih, w_hh, b_ih, b_hh, b_iah, b_oah, W_in, bias_in, W_out, bias_out,
        Wc, Whh, Wih, cstA, cstB, biasc);
    gru_fused<<<dim3(1024), dim3(512), 0, stream>>>(
        A, hidden, Wc, Whh, Wih, cstA, cstB, biasc, out);
}

// Round 11
// 152.879 us; speedup vs baseline: 1.7099x; 1.7099x over previous
//
#include <hip/hip_runtime.h>

typedef _Float16 f16;
typedef __attribute__((ext_vector_type(4))) _Float16 f16x4;
typedef __attribute__((ext_vector_type(8))) _Float16 f16x8;
typedef __attribute__((ext_vector_type(4))) float f32x4;

#define MFMA16(a, b, c) __builtin_amdgcn_mfma_f32_16x16x32_f16((a), (b), (c), 0, 0, 0)

__device__ __forceinline__ f16x8 cvt8(float4 a, float4 b) {
    f16x8 r;
    r[0] = (f16)a.x; r[1] = (f16)a.y; r[2] = (f16)a.z; r[3] = (f16)a.w;
    r[4] = (f16)b.x; r[5] = (f16)b.y; r[6] = (f16)b.z; r[7] = (f16)b.w;
    return r;
}

__device__ __forceinline__ f16x8 zero8() {
    f16x8 z;
#pragma unroll
    for (int q = 0; q < 8; ++q) z[q] = (f16)0.0f;
    return z;
}

// ---------------- pre-kernel: fp16 weights + fused bias constants into ws ----
__global__ void prep_kernel(const float* __restrict__ w_ih, const float* __restrict__ w_hh,
                            const float* __restrict__ b_ih, const float* __restrict__ b_hh,
                            const float* __restrict__ b_iah, const float* __restrict__ b_oah,
                            const float* __restrict__ W_in, const float* __restrict__ bias_in,
                            const float* __restrict__ W_out, const float* __restrict__ bias_out,
                            f16* __restrict__ Wc, f16* __restrict__ Whh, f16* __restrict__ Wih,
                            float* __restrict__ cstA, float* __restrict__ cstB,
                            float* __restrict__ biasc) {
    const int gid = blockIdx.x * 256 + threadIdx.x;
    const int gstride = gridDim.x * 256;
    for (int i = gid; i < 8192; i += gstride)
        Wc[i] = (f16)(i < 4096 ? W_in[i] : W_out[i - 4096]);
    for (int i = gid; i < 12288; i += gstride) Whh[i] = (f16)w_hh[i];   // [192][64]
    for (int i = gid; i < 24576; i += gstride) Wih[i] = (f16)w_ih[i];   // [192][128]
    for (int job = gid; job < 768; job += gstride) {
        const int g = job >> 2, q = job & 3;
        float s = (q == 0) ? b_ih[g] : 0.0f;
        const float* wr = w_ih + g * 128 + q * 32;
        for (int i = 0; i < 32; ++i)
            s += wr[i] * ((q * 32 + i < 64) ? b_iah[q * 32 + i] : b_oah[q * 32 + i - 64]);
        atomicAdd(&cstA[g], s);
    }
    for (int g = gid; g < 192; g += gstride) cstB[g] = b_hh[g];
    for (int j = gid; j < 128; j += gstride) biasc[j] = (j < 64) ? bias_in[j] : bias_out[j - 64];
}

__global__ void zero_kernel(float* __restrict__ cstA) {
    if (threadIdx.x < 192) cstA[threadIdx.x] = 0.0f;
}

// ---------------- fused main kernel (R3 structure, dbuf + 1 barrier/tile) ----
// DYNAMIC LDS 76800 B (needs hipFuncSetAttribute; 2 WGs/CU: 153.6 <= 160 KB):
//   hT  [128][200] f16 @0      (51200)  h_cat^T        (400-B rows: 16B-aligned)
//   hA  [2 buf][2 half][16][200] f16 @51200 (25600)    staged A tiles
//   inp [200][136] f16 @0      (54400)  aliases hT/hA-head after phase 2
// P2 schedule (full unroll, all parity static):
//   iter t: issue loads(t+2)->vset[t&1]; compute(t) from buf[t&1];
//           ds_write vset[(t+1)&1] -> buf[(t+1)&1]; ONE barrier.
// Load->use window ~1.5 tiles; 13 barriers instead of 26.
__global__ __launch_bounds__(512, 2) void gru_fused(
    const float* __restrict__ A, const float* __restrict__ hidden,
    const f16* __restrict__ Wc, const f16* __restrict__ Whh, const f16* __restrict__ Wih,
    const float* __restrict__ cstA, const float* __restrict__ cstB,
    const float* __restrict__ biasc, float* __restrict__ out) {
    extern __shared__ __align__(16) char lds_raw[];
    f16* hT  = (f16*)lds_raw;             // [128][200]
    f16* hA  = (f16*)(lds_raw + 51200);   // [2][2][16][200]
    f16* inp = (f16*)lds_raw;             // [200][136] alias

    const int b = blockIdx.x;
    const float* Ab = A + (size_t)b * 80000;      // [400][200]
    const float* hb = hidden + (size_t)b * 12800; // [200][64]
    float* ob = out + (size_t)b * 12800;

    const int tid = threadIdx.x;
    const int w   = tid >> 6;
    const int l   = tid & 63;
    const int l15 = l & 15;
    const int lg  = l >> 4;

    // ---- Phase 1: hT[j][m] = f16(hidden[m,:]@Wc[j,:] + biasc[j]) ----
    for (int mt = w; mt < 13; mt += 8) {
        const int m  = mt * 16 + l15;
        const int mc = m < 200 ? m : 199;
        const float* hrow = hb + mc * 64;
        float4 r0 = *(const float4*)(hrow + lg * 8);
        float4 r1 = *(const float4*)(hrow + lg * 8 + 4);
        float4 r2 = *(const float4*)(hrow + 32 + lg * 8);
        float4 r3 = *(const float4*)(hrow + 32 + lg * 8 + 4);
        f16x8 a0 = cvt8(r0, r1), a1 = cvt8(r2, r3);
        const int m0 = mt * 16 + lg * 4;
#pragma unroll
        for (int jt = 0; jt < 8; ++jt) {
            const int j = jt * 16 + l15;
            f32x4 acc = {0.f, 0.f, 0.f, 0.f};
            acc = MFMA16(a0, *(const f16x8*)(Wc + j * 64 + lg * 8), acc);
            acc = MFMA16(a1, *(const f16x8*)(Wc + j * 64 + 32 + lg * 8), acc);
            const float bc = biasc[j];
            if (m0 < 200) {
                f16x4 pk;
                pk[0] = (f16)(acc[0] + bc); pk[1] = (f16)(acc[1] + bc);
                pk[2] = (f16)(acc[2] + bc); pk[3] = (f16)(acc[3] + bc);
                *(f16x4*)(hT + j * 200 + m0) = pk;
            }
        }
    }
    __syncthreads();

    // ---- Phase 2: inputs = A_cat @ h_cat; dbuf, 1 barrier/tile -------------
    const int hf = w >> 2;
    const f16* hTp = hT + (w * 16 + l15) * 200;

    // staging map: 1600 float4-units (2 halves x 16 rows x 50 units)
    int s_h[4], s_row[4], s_unit[4]; bool s_act[4];
#pragma unroll
    for (int r = 0; r < 4; ++r) {
        const int idx = tid + r * 512;
        s_act[r] = idx < 1600;
        const int ic = s_act[r] ? idx : 0;
        s_h[r] = ic / 800;
        const int rem = ic % 800;
        s_row[r] = rem / 50; s_unit[r] = rem % 50;
    }

#define P2_LOADS(T, V)                                                            \
    {                                                                             \
        _Pragma("unroll")                                                         \
        for (int r = 0; r < 4; ++r) if (s_act[r]) {                               \
            const int n = (T) * 16 + s_row[r];                                    \
            const int nc = n < 200 ? n : 199;                                     \
            V[r] = *(const float4*)(Ab + (size_t)(s_h[r] * 200 + nc) * 200        \
                                    + s_unit[r] * 4);                             \
        }                                                                         \
    }
#define P2_WRITE(BUF, V)                                                          \
    {                                                                             \
        _Pragma("unroll")                                                         \
        for (int r = 0; r < 4; ++r) if (s_act[r]) {                               \
            const int idx = tid + r * 512;                                        \
            f16x4 pk;                                                             \
            pk[0] = (f16)V[r].x; pk[1] = (f16)V[r].y;                             \
            pk[2] = (f16)V[r].z; pk[3] = (f16)V[r].w;                             \
            *(f16x4*)(hA + (BUF) * 6400 + idx * 4) = pk;                          \
        }                                                                         \
    }

    f32x4 accC[13];
#pragma unroll
    for (int t = 0; t < 13; ++t) accC[t] = (f32x4){0.f, 0.f, 0.f, 0.f};

    float4 vA[4], vB[4];
    // prologue: tile0 -> buf0 (drained), tile1 loads in flight in vB
    P2_LOADS(0, vA);
    P2_WRITE(0, vA);
    P2_LOADS(1, vB);
    __syncthreads();

#pragma unroll
    for (int t = 0; t < 13; ++t) {
        // issue loads for tile t+2 into vset[t&1] (its old data already in LDS)
        if (t + 2 <= 12) {
            if ((t & 1) == 0) { P2_LOADS(t + 2, vA); }
            else              { P2_LOADS(t + 2, vB); }
        }
        // compute tile t from buf[t&1]
        {
            const f16* hAp = hA + (t & 1) * 6400 + hf * 3200 + l15 * 200;
#pragma unroll
            for (int k0 = 0; k0 < 224; k0 += 32) {
                const int koff = (k0 == 192) ? 192 : k0 + lg * 8;
                f16x8 a;
                if (k0 == 192 && lg != 0) a = zero8();
                else                      a = *(const f16x8*)(hAp + koff);
                f16x8 bf = *(const f16x8*)(hTp + koff);
                accC[t] = MFMA16(a, bf, accC[t]);
            }
        }
        // write tile t+1 (loaded at iter t-1 / prologue) into buf[(t+1)&1];
        // that buffer's last reads were tile t-1 (iter t-1), separated by the
        // barrier at the end of iter t-1.
        if (t + 1 <= 12) {
            if (((t + 1) & 1) == 0) { P2_WRITE(0, vA); }
            else                    { P2_WRITE(1, vB); }
        }
        __syncthreads();   // ONE barrier per tile
    }
#undef P2_LOADS
#undef P2_WRITE

    // spill accC -> inp (hT/hA dead now)
#pragma unroll
    for (int t = 0; t < 13; ++t) {
#pragma unroll
        for (int r = 0; r < 4; ++r) {
            const int n = t * 16 + lg * 4 + r;
            if (n < 200) inp[n * 136 + w * 16 + l15] = (f16)accC[t][r];
        }
    }
    __syncthreads();

    // ---- Phase 3: gi = inputs@w_ih^T, gh = hidden@w_hh^T, gates, store ----
    const int c   = w & 3;
    const int wm2 = w >> 2;
    const int hcol = c * 16 + l15;
    f16x8 Wf0[4], Wf1[4], Wf2[4];
#pragma unroll
    for (int k = 0; k < 4; ++k) {
        Wf0[k] = *(const f16x8*)(Wih + (hcol      ) * 128 + k * 32 + lg * 8);
        Wf1[k] = *(const f16x8*)(Wih + (64  + hcol) * 128 + k * 32 + lg * 8);
        Wf2[k] = *(const f16x8*)(Wih + (128 + hcol) * 128 + k * 32 + lg * 8);
    }
    f16x8 Hf0[2], Hf1[2], Hf2[2];
#pragma unroll
    for (int k = 0; k < 2; ++k) {
        Hf0[k] = *(const f16x8*)(Whh + (hcol      ) * 64 + k * 32 + lg * 8);
        Hf1[k] = *(const f16x8*)(Whh + (64  + hcol) * 64 + k * 32 + lg * 8);
        Hf2[k] = *(const f16x8*)(Whh + (128 + hcol) * 64 + k * 32 + lg * 8);
    }
    const float cAr = cstA[hcol], cAi = cstA[64 + hcol], cAn = cstA[128 + hcol];
    const float cBr = cstB[hcol], cBi = cstB[64 + hcol], cBn = cstB[128 + hcol];

    for (int t = wm2; t < 13; t += 2) {
        const int n  = t * 16 + l15;
        const int nc = n < 200 ? n : 199;
        f32x4 gir = {0.f,0.f,0.f,0.f}, gii = {0.f,0.f,0.f,0.f}, gin = {0.f,0.f,0.f,0.f};
        f32x4 ghr = {0.f,0.f,0.f,0.f}, ghi = {0.f,0.f,0.f,0.f}, ghn = {0.f,0.f,0.f,0.f};
#pragma unroll
        for (int k = 0; k < 2; ++k) {          // gh first: global loads issue early
            const int h = k * 32 + lg * 8;
            float4 r0 = *(const float4*)(hb + nc * 64 + h);
            float4 r1 = *(const float4*)(hb + nc * 64 + h + 4);
            f16x8 a = cvt8(r0, r1);
            ghr = MFMA16(a, Hf0[k], ghr);
            ghi = MFMA16(a, Hf1[k], ghi);
            ghn = MFMA16(a, Hf2[k], ghn);
        }
#pragma unroll
        for (int k = 0; k < 4; ++k) {          // gi: K = 128, inp in LDS
            f16x8 a = *(const f16x8*)(inp + nc * 136 + k * 32 + lg * 8);
            gir = MFMA16(a, Wf0[k], gir);
            gii = MFMA16(a, Wf1[k], gii);
            gin = MFMA16(a, Wf2[k], gin);
        }
#pragma unroll
        for (int r = 0; r < 4; ++r) {
            const int row = t * 16 + lg * 4 + r;
            if (row < 200) {
                const float hv = hb[row * 64 + hcol];
                const float xr = gir[r] + ghr[r] + cAr + cBr;
                const float xi = gii[r] + ghi[r] + cAi + cBi;
                const float rg = 1.0f / (1.0f + __expf(-xr));
                const float ig = 1.0f / (1.0f + __expf(-xi));
                const float xn = gin[r] + cAn + rg * (ghn[r] + cBn);
                const float e2 = __expf(2.0f * xn);
                const float ng = 1.0f - 2.0f / (e2 + 1.0f);
                ob[row * 64 + hcol] = hv + ig * (ng - hv);
            }
        }
    }
}

extern "C" void kernel_launch(void* const* d_in, const int* in_sizes, int n_in,
                              void* d_out, int out_size, void* d_ws, size_t ws_size,
                              hipStream_t stream) {
    const float* A        = (const float*)d_in[0];
    const float* hidden   = (const float*)d_in[1];
    const float* w_ih     = (const float*)d_in[2];
    const float* w_hh     = (const float*)d_in[3];
    const float* b_ih     = (const float*)d_in[4];
    const float* b_hh     = (const float*)d_in[5];
    const float* b_iah    = (const float*)d_in[6];
    const float* b_oah    = (const float*)d_in[7];
    const float* W_in     = (const float*)d_in[8];
    const float* bias_in  = (const float*)d_in[9];
    const float* W_out    = (const float*)d_in[10];
    const float* bias_out = (const float*)d_in[11];
    float* out = (float*)d_out;

    char* wsb = (char*)d_ws;
    f16* Wc      = (f16*)wsb;            // 8192 f16
    f16* Whh     = Wc + 8192;            // 12288 f16
    f16* Wih     = Whh + 12288;          // 24576 f16
    float* cstA  = (float*)(wsb + 90112);
    float* cstB  = cstA + 192;
    float* biasc = cstB + 192;

    // allow 76.8 KB dynamic LDS (host-side attribute, graph-capture safe)
    static const int kLds = 76800;
    hipFuncSetAttribute(reinterpret_cast<const void*>(gru_fused),
                        hipFuncAttributeMaxDynamicSharedMemorySize, kLds);

    zero_kernel<<<dim3(1), dim3(256), 0, stream>>>(cstA);
    prep_kernel<<<dim3(64), dim3(256), 0, stream>>>(
        w_ih, w_hh, b_ih, b_hh, b_iah, b_oah, W_in, bias_in, W_out, bias_out,
        Wc, Whh, Wih, cstA, cstB, biasc);
    gru_fused<<<dim3(1024), dim3(512), kLds, stream>>>(
        A, hidden, Wc, Whh, Wih, cstA, cstB, biasc, out);
}